// Round 5
// baseline (391.669 us; speedup 1.0000x reference)
//
#include <hip/hip_runtime.h>
#include <hip/hip_bf16.h>
#include <math.h>

// ---------------------------------------------------------------------------
// PalaceYiJingBlock — round 4: bf16-transposed weights, z-batched GEMMs,
// split-K for the 1-block/CU GEMMs, bf16 LN outputs.
// B=2, T=1024, D=1024, H=16, dh=64, Dff=4096.
// ---------------------------------------------------------------------------

typedef __attribute__((ext_vector_type(8))) __bf16 bf16x8_t;
typedef __attribute__((ext_vector_type(4))) float f32x4_t;

union PK2 { __bf16 h[4]; uint2 u; };
union PK4 { __bf16 h[8]; uint4 u; unsigned w[4]; bf16x8_t v; };

__device__ __forceinline__ int swz16(int row, int c) {
    return row * 64 + ((c ^ (row & 7)) << 3);
}
__device__ __forceinline__ int swzel(int row, int col) {
    return row * 64 + ((((col >> 3) ^ (row & 7))) << 3) + (col & 7);
}

__device__ __forceinline__ float block_reduce_sum(float v, float* sbuf) {
    for (int off = 32; off; off >>= 1) v += __shfl_down(v, off);
    int lane = threadIdx.x & 63, wid = threadIdx.x >> 6;
    if (lane == 0) sbuf[wid] = v;
    __syncthreads();
    float r = sbuf[0] + sbuf[1] + sbuf[2] + sbuf[3];
    __syncthreads();
    return r;
}

// ---- LayerNorm (bf16 out, z-batched over up to 2 param sets) --------------
struct LNP { const float* g[2]; const float* b[2]; __bf16* o[2]; };
__global__ __launch_bounds__(256) void ln_bf16(
    const float* __restrict__ x, LNP p, int D)
{
    __shared__ float sbuf[4];
    __shared__ float stats[2];
    int row = blockIdx.x, z = blockIdx.y;
    const float4* xr = (const float4*)(x + (size_t)row * D);
    int tid = threadIdx.x;
    int n4 = D >> 2;
    float sum = 0.f, sumsq = 0.f;
    for (int i = tid; i < n4; i += 256) {
        float4 v = xr[i];
        sum += v.x + v.y + v.z + v.w;
        sumsq += v.x * v.x + v.y * v.y + v.z * v.z + v.w * v.w;
    }
    float ts = block_reduce_sum(sum, sbuf);
    float tq = block_reduce_sum(sumsq, sbuf);
    if (tid == 0) {
        float m = ts / (float)D;
        float var = tq / (float)D - m * m;
        stats[0] = m;
        stats[1] = rsqrtf(var + 1e-5f);
    }
    __syncthreads();
    float m = stats[0], r = stats[1];
    const float4* gv = (const float4*)p.g[z];
    const float4* bv = (const float4*)p.b[z];
    __bf16* orow = p.o[z] + (size_t)row * D;
    for (int i = tid; i < n4; i += 256) {
        float4 v = xr[i];
        float4 gg = gv[i];
        float4 bb = bv[i];
        PK2 pk;
        pk.h[0] = (__bf16)((v.x - m) * r * gg.x + bb.x);
        pk.h[1] = (__bf16)((v.y - m) * r * gg.y + bb.y);
        pk.h[2] = (__bf16)((v.z - m) * r * gg.z + bb.z);
        pk.h[3] = (__bf16)((v.w - m) * r * gg.w + bb.w);
        *(uint2*)&orow[i * 4] = pk.u;
    }
}

// ---- convert+transpose: fp32 [K,N] -> bf16 [N,K], z-batched ---------------
struct CTP { const float* in[5]; __bf16* out[5]; };
__global__ __launch_bounds__(256) void convtrans(CTP p, int K, int N)
{
    __shared__ __bf16 tile[64 * 68];
    int k0 = blockIdx.x * 64, n0 = blockIdx.y * 64, z = blockIdx.z;
    const float* in = p.in[z];
    __bf16* out = p.out[z];
    int tid = threadIdx.x;
    #pragma unroll
    for (int q = 0; q < 4; ++q) {
        int e = tid + 256 * q; int r = e >> 4, c4 = e & 15;
        float4 v = *(const float4*)(in + (size_t)(k0 + r) * N + n0 + c4 * 4);
        PK2 pk;
        pk.h[0] = (__bf16)v.x; pk.h[1] = (__bf16)v.y;
        pk.h[2] = (__bf16)v.z; pk.h[3] = (__bf16)v.w;
        *(uint2*)&tile[r * 68 + c4 * 4] = pk.u;
    }
    __syncthreads();
    #pragma unroll
    for (int q = 0; q < 2; ++q) {
        int e = tid + 256 * q; int nn = e >> 3, kc = e & 7;
        PK4 pk;
        #pragma unroll
        for (int j = 0; j < 8; ++j) pk.h[j] = tile[(kc * 8 + j) * 68 + nn];
        *(uint4*)(out + (size_t)(n0 + nn) * K + k0 + kc * 8) = pk.u;
    }
}

// ---- bf16 GEMM, both operands bf16, Bt pre-transposed [N,K] ---------------
// BM=128,BN=64,BK=32; 4 waves 2x2, each 64x32 (4x2 frags 16x16x32).
// Batch mode: blockIdx.z selects gemm (A/B/bias/C arrays).
// Split mode: blockIdx.z selects K-slice; raw fp32 partial to P[z].
struct GP {
    const __bf16* A[4]; const __bf16* B[4];
    const float* bias[4]; __bf16* C[4];
    float* P[2];
};
template<bool GELU, bool SPLIT>
__global__ __launch_bounds__(256) void gemm_tt(
    GP g, int M, int N, int K, int kspan)
{
    __shared__ __bf16 Al[2][128 * 40];
    __shared__ __bf16 Bl[2][64 * 40];

    int zi = blockIdx.z;
    const __bf16* A  = SPLIT ? g.A[0] : g.A[zi];
    const __bf16* Bt = SPLIT ? g.B[0] : g.B[zi];
    int kbeg = SPLIT ? zi * kspan : 0;
    int nt = (SPLIT ? kspan : K) / 32;

    int tid = threadIdx.x;
    int bm = blockIdx.y * 128;
    int bn = blockIdx.x * 64;

    int sr = tid >> 2;         // staging row
    int sc = tid & 3;          // staging chunk (8 bf16)

    int w = tid >> 6;
    int wr = w >> 1, wc = w & 1;
    int lane = tid & 63;
    int fr = lane & 15;
    int fs = lane >> 4;

    uint4 aU[2], bU;
    auto loadT = [&](int k0) {
        #pragma unroll
        for (int p = 0; p < 2; ++p)
            aU[p] = *(const uint4*)(A + (size_t)(bm + sr + 64 * p) * K + k0 + sc * 8);
        bU = *(const uint4*)(Bt + (size_t)(bn + sr) * K + k0 + sc * 8);
    };
    auto writeT = [&](int buf) {
        #pragma unroll
        for (int p = 0; p < 2; ++p)
            *(uint4*)&Al[buf][(sr + 64 * p) * 40 + sc * 8] = aU[p];
        *(uint4*)&Bl[buf][sr * 40 + sc * 8] = bU;
    };

    loadT(kbeg);
    writeT(0);
    __syncthreads();

    f32x4_t acc[4][2];
    #pragma unroll
    for (int m = 0; m < 4; ++m)
        #pragma unroll
        for (int n = 0; n < 2; ++n)
            acc[m][n] = (f32x4_t){0.f, 0.f, 0.f, 0.f};

    for (int t = 0; t < nt; ++t) {
        int cur = t & 1;
        if (t + 1 < nt) loadT(kbeg + (t + 1) * 32);
        bf16x8_t af[4], bf[2];
        #pragma unroll
        for (int m = 0; m < 4; ++m)
            af[m] = *(bf16x8_t*)&Al[cur][(wr * 64 + m * 16 + fr) * 40 + fs * 8];
        #pragma unroll
        for (int n = 0; n < 2; ++n)
            bf[n] = *(bf16x8_t*)&Bl[cur][(wc * 32 + n * 16 + fr) * 40 + fs * 8];
        #pragma unroll
        for (int m = 0; m < 4; ++m)
            #pragma unroll
            for (int n = 0; n < 2; ++n)
                acc[m][n] = __builtin_amdgcn_mfma_f32_16x16x32_bf16(
                    af[m], bf[n], acc[m][n], 0, 0, 0);
        if (t + 1 < nt) writeT(cur ^ 1);
        __syncthreads();
    }

    if constexpr (SPLIT) {
        float* P = g.P[zi];
        #pragma unroll
        for (int m = 0; m < 4; ++m)
            #pragma unroll
            for (int n = 0; n < 2; ++n) {
                int col = bn + wc * 32 + n * 16 + fr;
                #pragma unroll
                for (int r = 0; r < 4; ++r) {
                    int row = bm + wr * 64 + m * 16 + fs * 4 + r;
                    P[(size_t)row * N + col] = acc[m][n][r];
                }
            }
    } else {
        const float* bias = g.bias[zi];
        __bf16* C = g.C[zi];
        #pragma unroll
        for (int m = 0; m < 4; ++m)
            #pragma unroll
            for (int n = 0; n < 2; ++n) {
                int col = bn + wc * 32 + n * 16 + fr;
                float bv = bias ? bias[col] : 0.f;
                #pragma unroll
                for (int r = 0; r < 4; ++r) {
                    int row = bm + wr * 64 + m * 16 + fs * 4 + r;
                    float val = acc[m][n][r] + bv;
                    if constexpr (GELU)
                        val = 0.5f * val * (1.0f + erff(val * 0.70710678118654752f));
                    C[(size_t)row * N + col] = (__bf16)val;
                }
            }
    }
}

// ---- finalize split-K: out = (p0+p1) + bias [+resid], bf16 or fp32 --------
template<bool OBF16, bool RESID>
__global__ __launch_bounds__(256) void finalize2(
    const float* __restrict__ p0, const float* __restrict__ p1,
    const float* __restrict__ bias, const float* __restrict__ resid,
    void* __restrict__ out, int N, int total4)
{
    int i = blockIdx.x * 256 + threadIdx.x;
    if (i >= total4) return;
    float4 a = ((const float4*)p0)[i];
    float4 b = ((const float4*)p1)[i];
    float4 bv = ((const float4*)bias)[i & (N / 4 - 1)];
    float4 s;
    s.x = a.x + b.x + bv.x;
    s.y = a.y + b.y + bv.y;
    s.z = a.z + b.z + bv.z;
    s.w = a.w + b.w + bv.w;
    if constexpr (RESID) {
        float4 rv = ((const float4*)resid)[i];
        s.x += rv.x; s.y += rv.y; s.z += rv.z; s.w += rv.w;
    }
    if constexpr (OBF16) {
        PK2 pk;
        pk.h[0] = (__bf16)s.x; pk.h[1] = (__bf16)s.y;
        pk.h[2] = (__bf16)s.z; pk.h[3] = (__bf16)s.w;
        ((uint2*)out)[i] = pk.u;
    } else {
        ((float4*)out)[i] = s;
    }
}

// ---- 64x64-tile bf16 transpose: in [b][t][D] -> out [b][d][T] -------------
__global__ __launch_bounds__(256) void transpose_bf16_64(
    const __bf16* __restrict__ in, __bf16* __restrict__ out, int T, int D)
{
    __shared__ __bf16 tile[64 * 66];
    int t0 = blockIdx.x * 64, d0 = blockIdx.y * 64, b = blockIdx.z;
    int tid = threadIdx.x;
    #pragma unroll
    for (int i = 0; i < 2; ++i) {
        int e = tid + 256 * i; int r = e >> 3, c = e & 7;
        PK4 pk;
        pk.u = *(const uint4*)(in + ((size_t)(b * T + t0 + r)) * D + d0 + c * 8);
        #pragma unroll
        for (int q = 0; q < 4; ++q)
            *(unsigned*)&tile[r * 66 + c * 8 + q * 2] = pk.w[q];
    }
    __syncthreads();
    #pragma unroll
    for (int i = 0; i < 2; ++i) {
        int e = tid + 256 * i; int dd = e >> 3, tch = e & 7;
        PK4 pk;
        #pragma unroll
        for (int j = 0; j < 8; ++j) pk.h[j] = tile[(tch * 8 + j) * 66 + dd];
        *(uint4*)(out + ((size_t)(b * D + d0 + dd)) * T + t0 + tch * 8) = pk.u;
    }
}

// ---- MFMA flash palace attention ------------------------------------------
__global__ __launch_bounds__(256) void attn_mfma(
    const __bf16* __restrict__ qb, const __bf16* __restrict__ kb,
    const __bf16* __restrict__ vt, const float* __restrict__ inter_w,
    __bf16* __restrict__ ao, int T, int H)
{
    __shared__ __bf16 Qs[64 * 64];
    __shared__ __bf16 Ks[64 * 64];
    __shared__ __bf16 Vs[64 * 64];
    __shared__ __bf16 Ps[64 * 64];

    int t0 = blockIdx.x * 64, h = blockIdx.y, b = blockIdx.z;
    int D = H * 64;
    int tid = threadIdx.x;
    int w = tid >> 6, lane = tid & 63, fr = lane & 15, fs = lane >> 4;
    float sw = 1.0f / (1.0f + __expf(-inter_w[0]));
    float mm[4];
    int palr = w * 2 + (fs >> 1);
    #pragma unroll
    for (int n = 0; n < 4; ++n)
        mm[n] = (palr == n * 2 + (fr >> 3)) ? 1.0f : sw;

    const __bf16* qbase = qb + ((size_t)b * T + t0) * D + h * 64;
    const __bf16* kbase = kb + (size_t)b * T * D + h * 64;
    const __bf16* vbase = vt + ((size_t)b * D + h * 64) * T;

    #pragma unroll
    for (int i = 0; i < 2; ++i) {
        int e = tid + 256 * i; int r = e >> 3, c = e & 7;
        PK4 pk; pk.u = *(const uint4*)(qbase + (size_t)r * D + c * 8);
        #pragma unroll
        for (int j = 0; j < 8; ++j) pk.h[j] = (__bf16)((float)pk.h[j] * 0.125f);
        *(uint4*)&Qs[swz16(r, c)] = pk.u;
    }

    f32x4_t acc[4];
    #pragma unroll
    for (int d = 0; d < 4; ++d) acc[d] = (f32x4_t){0.f, 0.f, 0.f, 0.f};
    float mrow[4] = {-1e30f, -1e30f, -1e30f, -1e30f};
    float lrow[4] = {0.f, 0.f, 0.f, 0.f};

    for (int s0 = 0; s0 < T; s0 += 64) {
        __syncthreads();
        #pragma unroll
        for (int i = 0; i < 2; ++i) {
            int e = tid + 256 * i; int r = e >> 3, c = e & 7;
            *(uint4*)&Ks[swz16(r, c)] = *(const uint4*)(kbase + (size_t)(s0 + r) * D + c * 8);
            *(uint4*)&Vs[swz16(r, c)] = *(const uint4*)(vbase + (size_t)r * T + s0 + c * 8);
        }
        __syncthreads();
        bf16x8_t aq0 = *(bf16x8_t*)&Qs[swz16(w * 16 + fr, fs)];
        bf16x8_t aq1 = *(bf16x8_t*)&Qs[swz16(w * 16 + fr, 4 + fs)];
        f32x4_t s4[4];
        #pragma unroll
        for (int n = 0; n < 4; ++n) {
            bf16x8_t b0 = *(bf16x8_t*)&Ks[swz16(n * 16 + fr, fs)];
            bf16x8_t b1 = *(bf16x8_t*)&Ks[swz16(n * 16 + fr, 4 + fs)];
            f32x4_t z = (f32x4_t){0.f, 0.f, 0.f, 0.f};
            z = __builtin_amdgcn_mfma_f32_16x16x32_bf16(aq0, b0, z, 0, 0, 0);
            s4[n] = __builtin_amdgcn_mfma_f32_16x16x32_bf16(aq1, b1, z, 0, 0, 0);
        }
        #pragma unroll
        for (int r_ = 0; r_ < 4; ++r_) {
            float mx = fmaxf(fmaxf(s4[0][r_], s4[1][r_]), fmaxf(s4[2][r_], s4[3][r_]));
            mx = fmaxf(mx, __shfl_xor(mx, 1));
            mx = fmaxf(mx, __shfl_xor(mx, 2));
            mx = fmaxf(mx, __shfl_xor(mx, 4));
            mx = fmaxf(mx, __shfl_xor(mx, 8));
            float mnew = fmaxf(mrow[r_], mx);
            float resc = __expf(mrow[r_] - mnew);
            mrow[r_] = mnew;
            float p0 = __expf(s4[0][r_] - mnew);
            float p1 = __expf(s4[1][r_] - mnew);
            float p2 = __expf(s4[2][r_] - mnew);
            float p3 = __expf(s4[3][r_] - mnew);
            float rs = p0 + p1 + p2 + p3;
            rs += __shfl_xor(rs, 1);
            rs += __shfl_xor(rs, 2);
            rs += __shfl_xor(rs, 4);
            rs += __shfl_xor(rs, 8);
            lrow[r_] = lrow[r_] * resc + rs;
            acc[0][r_] *= resc; acc[1][r_] *= resc;
            acc[2][r_] *= resc; acc[3][r_] *= resc;
            int prow = w * 16 + fs * 4 + r_;
            Ps[swzel(prow,  0 + fr)] = (__bf16)(p0 * mm[0]);
            Ps[swzel(prow, 16 + fr)] = (__bf16)(p1 * mm[1]);
            Ps[swzel(prow, 32 + fr)] = (__bf16)(p2 * mm[2]);
            Ps[swzel(prow, 48 + fr)] = (__bf16)(p3 * mm[3]);
        }
        bf16x8_t ap0 = *(bf16x8_t*)&Ps[swz16(w * 16 + fr, fs)];
        bf16x8_t ap1 = *(bf16x8_t*)&Ps[swz16(w * 16 + fr, 4 + fs)];
        #pragma unroll
        for (int d = 0; d < 4; ++d) {
            bf16x8_t b0 = *(bf16x8_t*)&Vs[swz16(d * 16 + fr, fs)];
            bf16x8_t b1 = *(bf16x8_t*)&Vs[swz16(d * 16 + fr, 4 + fs)];
            acc[d] = __builtin_amdgcn_mfma_f32_16x16x32_bf16(ap0, b0, acc[d], 0, 0, 0);
            acc[d] = __builtin_amdgcn_mfma_f32_16x16x32_bf16(ap1, b1, acc[d], 0, 0, 0);
        }
    }
    float inv[4];
    #pragma unroll
    for (int r_ = 0; r_ < 4; ++r_) inv[r_] = 1.0f / lrow[r_];
    #pragma unroll
    for (int d = 0; d < 4; ++d) {
        int col = h * 64 + d * 16 + fr;
        #pragma unroll
        for (int r_ = 0; r_ < 4; ++r_) {
            int row = t0 + w * 16 + fs * 4 + r_;
            ao[((size_t)b * T + row) * D + col] = (__bf16)(acc[d][r_] * inv[r_]);
        }
    }
}

// ---- GAT src/dst coefficients (bf16 input) --------------------------------
__global__ __launch_bounds__(256) void gat_coeff_kernel(
    const __bf16* __restrict__ hw, const float* __restrict__ a_src,
    const float* __restrict__ a_dst, float* __restrict__ sc,
    float* __restrict__ tc, int D)
{
    __shared__ float sbuf[4];
    int row = blockIdx.x;
    const __bf16* hr = hw + (size_t)row * D;
    float s1 = 0.f, s2 = 0.f;
    for (int i = threadIdx.x; i < D; i += 256) {
        float h = (float)hr[i];
        s1 += h * a_src[i];
        s2 += h * a_dst[i];
    }
    float t1 = block_reduce_sum(s1, sbuf);
    float t2 = block_reduce_sum(s2, sbuf);
    if (threadIdx.x == 0) { sc[row] = t1; tc[row] = t2; }
}

// ---- MFMA GAT aggregate ---------------------------------------------------
__global__ __launch_bounds__(256) void gat_agg_mfma(
    const __bf16* __restrict__ hwt, const float* __restrict__ sc,
    const float* __restrict__ tc, __bf16* __restrict__ hg, int T, int D)
{
    __shared__ __bf16 Hs[64 * 64];
    __shared__ float tcs[1024];
    __shared__ float red[4];
    __shared__ float zsh[64];

    int d0 = blockIdx.x * 64, t0 = blockIdx.y * 64, b = blockIdx.z;
    int tid = threadIdx.x;
    int w = tid >> 6, lane = tid & 63, fr = lane & 15, fs = lane >> 4;

    for (int i = tid; i < T; i += 256) tcs[i] = tc[(size_t)b * T + i];
    __syncthreads();
    float lm = -1e30f;
    for (int i = tid; i < T; i += 256) lm = fmaxf(lm, tcs[i]);
    for (int off = 32; off; off >>= 1) lm = fmaxf(lm, __shfl_down(lm, off));
    if (lane == 0) red[w] = lm;
    __syncthreads();
    float tmax = fmaxf(fmaxf(red[0], red[1]), fmaxf(red[2], red[3]));

    float sct = sc[(size_t)b * T + t0 + w * 16 + fr];
    float e0 = sct + tmax;
    float Mt = e0 > 0.f ? e0 : 0.2f * e0;
    float zl = 0.f;

    f32x4_t acc[4];
    #pragma unroll
    for (int d = 0; d < 4; ++d) acc[d] = (f32x4_t){0.f, 0.f, 0.f, 0.f};

    const __bf16* hb = hwt + ((size_t)b * D + d0) * T;

    for (int s0 = 0; s0 < T; s0 += 64) {
        __syncthreads();
        #pragma unroll
        for (int i = 0; i < 2; ++i) {
            int e = tid + 256 * i; int r = e >> 3, c = e & 7;
            *(uint4*)&Hs[swz16(r, c)] = *(const uint4*)(hb + (size_t)r * T + s0 + c * 8);
        }
        __syncthreads();
        bf16x8_t af[2];
        #pragma unroll
        for (int kk = 0; kk < 2; ++kk) {
            PK4 pk;
            #pragma unroll
            for (int j = 0; j < 8; ++j) {
                float e = sct + tcs[s0 + kk * 32 + fs * 8 + j];
                e = e > 0.f ? e : 0.2f * e;
                float p = __expf(e - Mt);
                zl += p;
                pk.h[j] = (__bf16)p;
            }
            af[kk] = pk.v;
        }
        #pragma unroll
        for (int d = 0; d < 4; ++d) {
            bf16x8_t b0 = *(bf16x8_t*)&Hs[swz16(d * 16 + fr, fs)];
            bf16x8_t b1 = *(bf16x8_t*)&Hs[swz16(d * 16 + fr, 4 + fs)];
            acc[d] = __builtin_amdgcn_mfma_f32_16x16x32_bf16(af[0], b0, acc[d], 0, 0, 0);
            acc[d] = __builtin_amdgcn_mfma_f32_16x16x32_bf16(af[1], b1, acc[d], 0, 0, 0);
        }
    }
    zl += __shfl_xor(zl, 16);
    zl += __shfl_xor(zl, 32);
    if (lane < 16) zsh[w * 16 + fr] = zl;
    __syncthreads();
    #pragma unroll
    for (int r_ = 0; r_ < 4; ++r_) {
        float invz = 1.0f / zsh[w * 16 + fs * 4 + r_];
        int row = t0 + w * 16 + fs * 4 + r_;
        #pragma unroll
        for (int d = 0; d < 4; ++d)
            hg[((size_t)b * T + row) * D + d0 + d * 16 + fr] = (__bf16)(acc[d][r_] * invz);
    }
}

// ---- gated fusion: x2 = x + a*hp + (1-a)*hg -------------------------------
__global__ __launch_bounds__(256) void fuse_kernel(
    const float* __restrict__ x, const __bf16* __restrict__ hp,
    const __bf16* __restrict__ hg, const float* __restrict__ gate,
    float* __restrict__ x2, int n8)
{
    int i = blockIdx.x * 256 + threadIdx.x;
    if (i >= n8) return;
    float a = 1.0f / (1.0f + __expf(-gate[0]));
    float om = 1.0f - a;
    PK4 p, g;
    p.u = *(const uint4*)(hp + (size_t)i * 8);
    g.u = *(const uint4*)(hg + (size_t)i * 8);
    const float4* xv = (const float4*)(x + (size_t)i * 8);
    float4* ov = (float4*)(x2 + (size_t)i * 8);
    float4 x0 = xv[0], x1 = xv[1], o0, o1;
    o0.x = x0.x + a * (float)p.h[0] + om * (float)g.h[0];
    o0.y = x0.y + a * (float)p.h[1] + om * (float)g.h[1];
    o0.z = x0.z + a * (float)p.h[2] + om * (float)g.h[2];
    o0.w = x0.w + a * (float)p.h[3] + om * (float)g.h[3];
    o1.x = x1.x + a * (float)p.h[4] + om * (float)g.h[4];
    o1.y = x1.y + a * (float)p.h[5] + om * (float)g.h[5];
    o1.z = x1.z + a * (float)p.h[6] + om * (float)g.h[6];
    o1.w = x1.w + a * (float)p.h[7] + om * (float)g.h[7];
    ov[0] = o0; ov[1] = o1;
}

// ---------------------------------------------------------------------------
extern "C" void kernel_launch(void* const* d_in, const int* in_sizes, int n_in,
                              void* d_out, int out_size, void* d_ws, size_t ws_size,
                              hipStream_t stream) {
    const float* x      = (const float*)d_in[0];
    const float* Wq     = (const float*)d_in[1];
    const float* bq     = (const float*)d_in[2];
    const float* Wk     = (const float*)d_in[3];
    const float* bk     = (const float*)d_in[4];
    const float* Wv     = (const float*)d_in[5];
    const float* bv     = (const float*)d_in[6];
    const float* Wo     = (const float*)d_in[7];
    const float* bo     = (const float*)d_in[8];
    const float* interw = (const float*)d_in[9];
    const float* Wg     = (const float*)d_in[10];
    const float* a_src  = (const float*)d_in[11];
    const float* a_dst  = (const float*)d_in[12];
    const float* g1     = (const float*)d_in[13];
    const float* b1     = (const float*)d_in[14];
    const float* g2     = (const float*)d_in[15];
    const float* b2     = (const float*)d_in[16];
    const float* g3     = (const float*)d_in[17];
    const float* b3     = (const float*)d_in[18];
    const float* gate   = (const float*)d_in[19];
    const float* W1     = (const float*)d_in[20];
    const float* bf1    = (const float*)d_in[21];
    const float* W2     = (const float*)d_in[22];
    const float* bf2    = (const float*)d_in[23];

    const int D   = in_sizes[2];           // 1024
    const int BT  = in_sizes[0] / D;       // 2048
    const int T   = 1024;
    const int B   = BT / T;                // 2
    const int H   = 16;
    const int Dff = in_sizes[21];          // 4096

    const size_t MB = 1024 * 1024;
    char* wsb = (char*)d_ws;
    // activation slots (lifetimes disjoint where overlaid)
    __bf16* h1   = (__bf16*)(wsb + 0 * MB);   // LN1 -> QKVG
    __bf16* h2   = (__bf16*)(wsb + 4 * MB);   // LN2 -> QKVG
    __bf16* qb   = (__bf16*)(wsb + 8 * MB);   // QKVG -> attn
    __bf16* kb   = (__bf16*)(wsb + 12 * MB);  // QKVG -> attn
    __bf16* vb   = (__bf16*)(wsb + 16 * MB);  // QKVG -> vT
    __bf16* hw   = (__bf16*)(wsb + 20 * MB);  // QKVG -> coeff/hwT
    __bf16* vt   = (__bf16*)(wsb + 24 * MB);  // vT -> attn
    __bf16* hwt  = (__bf16*)(wsb + 28 * MB);  // hwT -> gat_agg
    __bf16* ao   = (__bf16*)(wsb + 0 * MB);   // attn -> Wo (over h1)
    __bf16* hg   = (__bf16*)(wsb + 12 * MB);  // gat_agg -> fuse (over kb)
    float*  pWo0 = (float*)(wsb + 16 * MB);   // Wo partials (over vb+hw)
    float*  pWo1 = (float*)(wsb + 24 * MB);   //             (over vt+hwt)
    __bf16* hp   = (__bf16*)(wsb + 8 * MB);   // finWo -> fuse (over qb)
    float*  x2   = (float*)(wsb + 32 * MB);   // fuse -> finW2
    __bf16* hf   = (__bf16*)(wsb + 4 * MB);   // LN3 -> W1 (over h2)
    __bf16* mid  = (__bf16*)(wsb + 16 * MB);  // W1 -> W2 (16MB, over pWo)
    float*  pW20 = (float*)(wsb + 40 * MB);   // W2 partial (over W1t)
    float*  pW21 = (float*)(wsb + 0 * MB);    // W2 partial (over ao+hf)
    // weights (bf16, transposed [N,K])
    __bf16* W1t  = (__bf16*)(wsb + 40 * MB);  // 8MB (dead after W1 gemm)
    __bf16* W2t  = (__bf16*)(wsb + 48 * MB);  // 8MB
    __bf16* Wqt  = (__bf16*)(wsb + 56 * MB);
    __bf16* Wkt  = (__bf16*)(wsb + 58 * MB);
    __bf16* Wvt  = (__bf16*)(wsb + 60 * MB);
    __bf16* Wot  = (__bf16*)(wsb + 62 * MB);
    __bf16* Wgt  = (__bf16*)(wsb + 64 * MB);
    float*  scb  = (float*)(wsb + 66 * MB);
    float*  tcb  = scb + BT;

    dim3 blk(256);

    // ---- weight prep: convert+transpose to bf16 [N,K] ----
    {
        CTP p;
        p.in[0] = Wq; p.in[1] = Wk; p.in[2] = Wv; p.in[3] = Wo; p.in[4] = Wg;
        p.out[0] = Wqt; p.out[1] = Wkt; p.out[2] = Wvt; p.out[3] = Wot; p.out[4] = Wgt;
        convtrans<<<dim3(D / 64, D / 64, 5), blk, 0, stream>>>(p, D, D);
        CTP p1; p1.in[0] = W1; p1.out[0] = W1t;
        convtrans<<<dim3(D / 64, Dff / 64, 1), blk, 0, stream>>>(p1, D, Dff);
        CTP p2; p2.in[0] = W2; p2.out[0] = W2t;
        convtrans<<<dim3(Dff / 64, D / 64, 1), blk, 0, stream>>>(p2, Dff, D);
    }

    // ---- LN1 + LN2 (batched) ----
    {
        LNP p;
        p.g[0] = g1; p.b[0] = b1; p.o[0] = h1;
        p.g[1] = g2; p.b[1] = b2; p.o[1] = h2;
        ln_bf16<<<dim3(BT, 2), blk, 0, stream>>>(x, p, D);
    }

    // ---- QKV + Wg projections, one batched launch (4 blocks/CU) ----
    {
        GP g = {};
        g.A[0] = h1; g.B[0] = Wqt; g.bias[0] = bq; g.C[0] = qb;
        g.A[1] = h1; g.B[1] = Wkt; g.bias[1] = bk; g.C[1] = kb;
        g.A[2] = h1; g.B[2] = Wvt; g.bias[2] = bv; g.C[2] = vb;
        g.A[3] = h2; g.B[3] = Wgt; g.bias[3] = nullptr; g.C[3] = hw;
        gemm_tt<false, false><<<dim3(D / 64, BT / 128, 4), blk, 0, stream>>>(
            g, BT, D, D, 0);
    }

    // ---- transposes + GAT coeffs ----
    transpose_bf16_64<<<dim3(T / 64, D / 64, B), blk, 0, stream>>>(vb, vt, T, D);
    transpose_bf16_64<<<dim3(T / 64, D / 64, B), blk, 0, stream>>>(hw, hwt, T, D);
    gat_coeff_kernel<<<BT, blk, 0, stream>>>(hw, a_src, a_dst, scb, tcb, D);

    // ---- attention + GAT aggregate ----
    attn_mfma<<<dim3(T / 64, H, B), blk, 0, stream>>>(qb, kb, vt, interw, ao, T, H);
    gat_agg_mfma<<<dim3(D / 64, T / 64, B), blk, 0, stream>>>(hwt, scb, tcb, hg, T, D);

    // ---- Wo projection: split-K=2 + finalize ----
    {
        GP g = {};
        g.A[0] = ao; g.B[0] = Wot;
        g.P[0] = pWo0; g.P[1] = pWo1;
        gemm_tt<false, true><<<dim3(D / 64, BT / 128, 2), blk, 0, stream>>>(
            g, BT, D, D, D / 2);
        int total4 = BT * D / 4;
        finalize2<true, false><<<(total4 + 255) / 256, blk, 0, stream>>>(
            pWo0, pWo1, bo, nullptr, hp, D, total4);
    }

    // ---- gated fusion + LN3 ----
    int n8 = (int)((size_t)BT * D / 8);
    fuse_kernel<<<(n8 + 255) / 256, blk, 0, stream>>>(x, hp, hg, gate, x2, n8);
    {
        LNP p;
        p.g[0] = g3; p.b[0] = b3; p.o[0] = hf;
        p.g[1] = g3; p.b[1] = b3; p.o[1] = hf;   // unused z=1
        ln_bf16<<<dim3(BT, 1), blk, 0, stream>>>(x2, p, D);
    }

    // ---- FFN: W1 (GELU, 4 blocks/CU), W2 split-K=2 + finalize(resid) ----
    {
        GP g = {};
        g.A[0] = hf; g.B[0] = W1t; g.bias[0] = bf1; g.C[0] = mid;
        gemm_tt<true, false><<<dim3(Dff / 64, BT / 128, 1), blk, 0, stream>>>(
            g, BT, Dff, D, 0);
    }
    {
        GP g = {};
        g.A[0] = mid; g.B[0] = W2t;
        g.P[0] = pW20; g.P[1] = pW21;
        gemm_tt<false, true><<<dim3(D / 64, BT / 128, 2), blk, 0, stream>>>(
            g, BT, D, Dff, Dff / 2);
        int total4 = BT * D / 4;
        finalize2<false, true><<<(total4 + 255) / 256, blk, 0, stream>>>(
            pW20, pW21, bf2, x2, d_out, D, total4);
    }
}